// Round 6
// baseline (80.058 us; speedup 1.0000x reference)
//
#include <hip/hip_runtime.h>

#define MAXT 100000.0f

constexpr int B    = 64;
constexpr int IN   = 1024;
constexpr int N    = 1025;   // IN + bias column
constexpr int OUTS = 512;
constexpr int NSEG = 8;      // waves per block (512 threads)
constexpr int NGRP = 16;     // scan groups (half-waves), 64 rows each
constexpr int GRPL = 64;     // rows per group; rank 1024 is group-15 tail
constexpr int JCH  = 32;     // j columns per block (1 per thread-of-group)
constexpr unsigned KEYMASK = 0xFFFFFC00u;  // top 22 value bits | 10-bit index
constexpr unsigned BIASKEY = 0x3F8003FFu;  // key upper bound for bias rank

struct alignas(8) Pair { unsigned off; unsigned x; };
struct alignas(16) Pair2 { Pair a, b; };   // one ds_read_b128

// ---------------- Fused: per-row sort + gathered-weight scan ----------------
// R12: single-read weights. R11 (76.25 us) read each weight twice (pass-1
// sums + pass-2 scan) = 268 MB L2 traffic (~7.8 us floor). Here each thread
// holds its group's 64 weights in registers across the prefix barrier ->
// one read (134 MB, ~3.9 us floor); pass 2 becomes pure VALU+LDS and
// overlaps the co-resident block's load phase (R11's proven mechanism).
// Geometry forced by VGPR budget: 16 groups x 64 rows, 1 col/thread,
// JCH=32, grid (64,16) = 1024 blocks = 2 rounds of 2 blocks/CU.
//  * sort: byte-identical to R11 (HW-validated); redundancy 16x, overlapped
//  * pass 1: 64 scalar loads -> wreg[64] (static idx, full unroll) + sums
//  * pass 2: wreg + pipelined Pair2 LDS reads, R8 h-recurrence algebra
//  * reduce: LDS atomicMin (int bits of nonneg floats)
__global__ __launch_bounds__(512, 4) void snn_fused(
    const float* __restrict__ layer_in,
    const float* __restrict__ weight,
    const float* __restrict__ delay,
    float* __restrict__ out) {
  __shared__ unsigned ksh[2][IN];            // double-buffered sort exchange
  __shared__ float vsh[IN];
  __shared__ __align__(16) Pair ps[N + 1];
  __shared__ float2 red2[NGRP][JCH];         // per-group (sum w, sum w*x)
  __shared__ __align__(16) int redm[JCH];    // final min (int bits)

  const int b    = blockIdx.x;
  const int jc   = blockIdx.y;         // 0..15, 32 cols each
  const int lane = threadIdx.x;        // 0..63
  const int seg  = threadIdx.y;        // 0..7 (wave id)
  const int tid  = seg * 64 + lane;
  const int g    = seg * 2 + (lane >> 5);    // scan group 0..15
  const int c    = lane & 31;                // column within block
  const unsigned jadd = (unsigned)((jc * JCH + c) * 4);   // byte offset

  if (tid < JCH) redm[tid] = __float_as_int(MAXT);  // fenced by sort barriers

  // ---- Phase A: scaled input + 2-elem/thread bitonic argsort (R11 code) ----
  // Thread (lane, seg) owns virtual positions v0 = seg*128+lane (bit6=0) and
  // v1 = v0+64 (bit6=1). Stage (kk,jj): jj<=32 -> shfl; jj==64 -> in-thread;
  // jj>=128 -> LDS (double-buffered, one barrier per round; lds2 fuses pairs).
  {
    const int v0 = seg * 128 + lane;
    const int v1 = v0 + 64;
    float d0 = delay[v0], d1 = delay[v1];
    float x0 = layer_in[b * IN + v0] * expf(d0 > 0.0f ? d0 : 0.0f);
    float x1 = layer_in[b * IN + v1] * expf(d1 > 0.0f ? d1 : 0.0f);
    vsh[v0] = x0; vsh[v1] = x1;
    unsigned k0 = (__float_as_uint(x0) & KEYMASK) | (unsigned)v0;
    unsigned k1 = (__float_as_uint(x1) & KEYMASK) | (unsigned)v1;

    auto sop = [](unsigned x, unsigned y, bool tmin) {
      unsigned mn = x < y ? x : y;
      unsigned mx = x < y ? y : x;
      return tmin ? mn : mx;
    };
    int pb = 0;
    auto shflst = [&](int KK, int JJ) {     // JJ <= 32
      unsigned o0 = __shfl_xor(k0, JJ, 64);
      unsigned o1 = __shfl_xor(k1, JJ, 64);
      k0 = sop(k0, o0, ((v0 & KK) == 0) == ((v0 & JJ) == 0));
      k1 = sop(k1, o1, ((v1 & KK) == 0) == ((v1 & JJ) == 0));
    };
    auto local64 = [&](int KK) {            // jj == 64: partner is in-thread
      bool up = ((v0 & KK) == 0);
      unsigned mn = k0 < k1 ? k0 : k1;
      unsigned mx = k0 < k1 ? k1 : k0;
      k0 = up ? mn : mx;
      k1 = up ? mx : mn;
    };
    auto lds1 = [&](int KK, int JJ) {
      ksh[pb][v0] = k0; ksh[pb][v1] = k1;
      __syncthreads();
      unsigned o0 = ksh[pb][v0 ^ JJ];
      unsigned o1 = ksh[pb][v1 ^ JJ];
      pb ^= 1;
      k0 = sop(k0, o0, ((v0 & KK) == 0) == ((v0 & JJ) == 0));
      k1 = sop(k1, o1, ((v1 & KK) == 0) == ((v1 & JJ) == 0));
    };
    auto lds2 = [&](int KK, int JJ) {       // fused (JJ, JJ/2) stage pair
      int J2 = JJ >> 1;
      ksh[pb][v0] = k0; ksh[pb][v1] = k1;
      __syncthreads();
      {
        unsigned o = ksh[pb][v0 ^ JJ];
        unsigned a = ksh[pb][v0 ^ J2];
        unsigned cc = ksh[pb][v0 ^ (JJ | J2)];
        bool up = ((v0 & KK) == 0);
        bool s1 = up == ((v0 & JJ) == 0);
        unsigned kq = sop(k0, o, s1);
        unsigned kp = sop(a, cc, s1);
        k0 = sop(kq, kp, up == ((v0 & J2) == 0));
      }
      {
        unsigned o = ksh[pb][v1 ^ JJ];
        unsigned a = ksh[pb][v1 ^ J2];
        unsigned cc = ksh[pb][v1 ^ (JJ | J2)];
        bool up = ((v1 & KK) == 0);
        bool s1 = up == ((v1 & JJ) == 0);
        unsigned kq = sop(k1, o, s1);
        unsigned kp = sop(a, cc, s1);
        k1 = sop(kq, kp, up == ((v1 & J2) == 0));
      }
      pb ^= 1;
    };
    auto tailw = [&](int KK) {              // jj = 32..1
#pragma unroll
      for (int jj = 32; jj > 0; jj >>= 1) shflst(KK, jj);
    };

#pragma unroll
    for (int kk = 2; kk <= 64; kk <<= 1)
#pragma unroll
      for (int jj = kk >> 1; jj > 0; jj >>= 1) shflst(kk, jj);

    local64(128);                       tailw(128);
    lds1(256, 128);   local64(256);     tailw(256);
    lds2(512, 256);   local64(512);     tailw(512);
    lds2(1024, 512);  lds1(1024, 128);  local64(1024);  tailw(1024);

    // bias (x=1.0, idx=IN) rank: elements split across k0/k1 -> two counts
    int r = __syncthreads_count((k0 <= BIASKEY) ? 1 : 0)
          + __syncthreads_count((k1 <= BIASKEY) ? 1 : 0);

    int idx0 = (int)(k0 & 1023u);
    int idx1 = (int)(k1 & 1023u);
    float xs0 = vsh[idx0];
    float xs1 = vsh[idx1];
    int p0 = v0 + (v0 >= r);
    int p1 = v1 + (v1 >= r);
    Pair pr0; pr0.off = (unsigned)(idx0 * OUTS * 4); pr0.x = __float_as_uint(xs0);
    Pair pr1; pr1.off = (unsigned)(idx1 * OUTS * 4); pr1.x = __float_as_uint(xs1);
    ps[p0] = pr0;
    ps[p1] = pr1;
    if (tid == 0) {
      Pair bias; bias.off = (unsigned)(IN * OUTS * 4); bias.x = __float_as_uint(1.0f);
      ps[r] = bias;
      Pair sent; sent.off = 0u; sent.x = __float_as_uint(MAXT);
      ps[N] = sent;
    }
    __syncthreads();
  }

  // ---- Phase B ----
  const char* wbase = (const char*)weight;
  const int is = g * GRPL;

  // Pass 1: load this group's 64 weights for column c ONCE into registers,
  // accumulating (sum w, sum w*x). Static indices via full unroll (rule:
  // runtime-indexed register arrays spill to scratch). Each thread owns its
  // column -> no cross-lane combine needed; all 16 groups publish sums.
  float wreg[GRPL];
  {
    float sw = 0.0f, sx = 0.0f;
#pragma unroll
    for (int u = 0; u < GRPL; ++u) {
      Pair p = ps[is + u];                 // uniform per half-wave: broadcast
      float w = *(const float*)(wbase + (p.off + jadd));
      wreg[u] = w;
      sw += w;
      sx = fmaf(w, __uint_as_float(p.x), sx);
    }
    red2[g][c] = make_float2(sw, sx);
  }
  // Tail weight (rank 1024) for the last group, issued before the barrier so
  // its latency hides under the barrier + prefix math.
  float wt = 0.0f;
  if (g == NGRP - 1) {
    Pair pt = ps[N - 1];
    wt = *(const float*)(wbase + (pt.off + jadd));
  }
  __syncthreads();

  // Exclusive prefix over groups; wc holds w_cum - 1.
  float wc = -1.0f, wi = 0.0f;
  for (int s = 0; s < g; ++s) {
    float2 t = red2[s][c];
    wc += t.x; wi += t.y;
  }

  // Pass 2: pure VALU+LDS scan over the held weights.
  // valid(u) <=> min(wc, -h_prev, h, -bd) >= 0 with h = x_{u+1}*wc - wi
  // (identity: g_{u+1} == -h_u exactly); xs sorted => first valid IS the
  // filtered min (R8 algebra, HW-validated).
  float bn = MAXT, bd = -1.0f;
  Pair2 t0 = *(const Pair2*)(ps + is);
  float xa = __uint_as_float(t0.a.x);
  float xb = __uint_as_float(t0.b.x);
  float hp = fmaf(xa, wc, -wi);

#pragma unroll
  for (int u = 0; u < GRPL; u += 2) {
    Pair2 nx = *(const Pair2*)(ps + is + u + 2);   // rows u+2,u+3 (b128)
    {  // row u: w=wreg[u], xi=xa, xn=xb
      wc += wreg[u]; wi = fmaf(wreg[u], xa, wi);
      float h  = fmaf(xb, wc, -wi);
      float qq = fminf(fminf(wc, -hp), fminf(h, -bd));
      bool f = qq >= 0.0f;
      bn = f ? wi : bn;  bd = f ? wc : bd;  hp = h;
    }
    float xc = __uint_as_float(nx.a.x);
    {  // row u+1: w=wreg[u+1], xi=xb, xn=xc
      wc += wreg[u + 1]; wi = fmaf(wreg[u + 1], xb, wi);
      float h  = fmaf(xc, wc, -wi);
      float qq = fminf(fminf(wc, -hp), fminf(h, -bd));
      bool f = qq >= 0.0f;
      bn = f ? wi : bn;  bd = f ? wc : bd;  hp = h;
    }
    xa = xc; xb = __uint_as_float(nx.b.x);
  }
  // Loop exit: xa = x[is+64], xb = x[is+65]. For g==15: xa = x[1024],
  // xb = MAXT sentinel -> global tail row rank 1024.
  if (g == NGRP - 1) {
    wc += wt; wi = fmaf(wt, xa, wi);
    float h  = fmaf(xb, wc, -wi);
    float qq = fminf(fminf(wc, -hp), fminf(h, -bd));
    bool f = qq >= 0.0f;
    bn = f ? wi : bn;  bd = f ? wc : bd;
  }
  float best = (bd < 0.0f) ? MAXT : bn * __builtin_amdgcn_rcpf(fmaxf(bd, 1e-10f));

  // Candidates are nonneg floats <= MAXT -> int-bit atomicMin == float min.
  atomicMin(&redm[c], __float_as_int(best));
  __syncthreads();
  if (tid < JCH / 4) {
    int4 mv = *(const int4*)(&redm[tid * 4]);
    float4 o = make_float4(__int_as_float(mv.x), __int_as_float(mv.y),
                           __int_as_float(mv.z), __int_as_float(mv.w));
    *(float4*)(&out[b * OUTS + jc * JCH + tid * 4]) = o;
  }
}

extern "C" void kernel_launch(void* const* d_in, const int* in_sizes, int n_in,
                              void* d_out, int out_size, void* d_ws, size_t ws_size,
                              hipStream_t stream) {
  const float* layer_in = (const float*)d_in[0];
  const float* weight   = (const float*)d_in[1];
  const float* delay    = (const float*)d_in[2];
  float* out = (float*)d_out;
  (void)d_ws; (void)ws_size;

  snn_fused<<<dim3(B, OUTS / JCH), dim3(64, NSEG), 0, stream>>>(
      layer_in, weight, delay, out);
}